// Round 20
// baseline (737.605 us; speedup 1.0000x reference)
//
#include <hip/hip_runtime.h>

typedef _Float16 h2_t __attribute__((ext_vector_type(2)));
typedef _Float16 f16x4v __attribute__((ext_vector_type(4)));
typedef _Float16 f16x8 __attribute__((ext_vector_type(8)));
typedef float f32x4 __attribute__((ext_vector_type(4)));

struct F8pair { f16x4v lo, hi; };
static __device__ __forceinline__ f16x8 ldfrag(const _Float16* p) {
    F8pair r;
    r.lo = *(const f16x4v*)p;
    r.hi = *(const f16x4v*)(p + 4);
    return __builtin_bit_cast(f16x8, r);
}

static __device__ __forceinline__ unsigned int pkrtz(float a, float b) {
    return __builtin_bit_cast(unsigned int, __builtin_amdgcn_cvt_pkrtz(a, b));
}

static __device__ __forceinline__ float h2lo(unsigned int w) {
    h2_t h = __builtin_bit_cast(h2_t, w);
    return (float)h.x;
}
static __device__ __forceinline__ float h2hi(unsigned int w) {
    h2_t h = __builtin_bit_cast(h2_t, w);
    return (float)h.y;
}

// build f16x8 A-fragment from 8 consecutive fp32 values
static __device__ __forceinline__ f16x8 mkfrag(const float* p) {
    float4 a = ((const float4*)p)[0];
    float4 b = ((const float4*)p)[1];
    uint4 u;
    u.x = pkrtz(a.x, a.y); u.y = pkrtz(a.z, a.w);
    u.z = pkrtz(b.x, b.y); u.w = pkrtz(b.z, b.w);
    return __builtin_bit_cast(f16x8, u);
}

// ---------------- precompute: folded + transposed fp16 weights ----------------
__global__ void k_pre(const float* __restrict__ W_src, const float* __restrict__ W_dst,
                      const float* __restrict__ Wa1, const float* __restrict__ ba1,
                      const float* __restrict__ Wp2, const float* __restrict__ bp2,
                      const float* __restrict__ Wa2, const float* __restrict__ W_in,
                      const float* __restrict__ W_lin, const float* __restrict__ W_out,
                      float* __restrict__ bias2, _Float16* __restrict__ Wcat,
                      _Float16* __restrict__ Wnode, _Float16* __restrict__ WoutT)
{
    int idx = blockIdx.x * 256 + threadIdx.x;
    if (idx < 64) {
        int l = idx;
        float a = ba1[l];
        for (int c = 0; c < 128; ++c) a = fmaf(bp2[c], Wa1[c*64+l], a);
        bias2[l] = a;
    } else if (idx < 64 + 21760) {
        int j = idx - 64;
        int row = j / 68, k = j % 68;
        float val = 0.f;
        if (k < 64) {
            if (row < 64) {
                int Q = 2 * (row & 31) + (row >> 5);
                float a = 0.f;
                for (int c = 0; c < 128; ++c) a = fmaf(Wp2[k*128+c], Wa1[c*64+Q], a);
                val = a;
            } else if (row < 192) {
                int cpos = row - 64;
                int P = 2 * (cpos & 63) + (cpos >> 6);
                val = Wp2[k*128 + P];
            } else {
                int cpos = row - 192;
                int P = 2 * (cpos & 63) + (cpos >> 6);
                int Qk = 2 * (k & 31) + (k >> 5);
                val = Wa2[Qk*128 + P];
            }
        }
        Wcat[j] = (_Float16)val;
    } else if (idx < 21824 + 16896) {          // WinT
        int j = idx - 21824;
        int c = j / 132, k = j % 132;
        Wnode[j] = (_Float16)((k < 128) ? W_in[k*128+c] : 0.f);
    } else if (idx < 38720 + 16896) {          // WlinT
        int j = idx - 38720;
        int c = j / 132, k = j % 132;
        Wnode[16896 + j] = (_Float16)((k < 128) ? W_lin[k*128+c] : 0.f);
    } else if (idx < 55616 + 16896) {          // WpsdT (folded)
        int j = idx - 55616;
        int c = j / 132, k = j % 132;
        float val = 0.f;
        if (k < 128) {
            if (c < 64) {
                for (int q = 0; q < 128; ++q) val = fmaf(W_src[k*128+q], Wa1[q*64+c], val);
            } else {
                for (int q = 0; q < 128; ++q) val = fmaf(W_dst[k*128+q], Wa1[q*64+(c-64)], val);
            }
        }
        Wnode[33792 + j] = (_Float16)val;
    } else if (idx < 72512 + 16896) {          // WoutT
        int j = idx - 72512;
        int c = j / 132, k = j % 132;
        WoutT[j] = (_Float16)((k < 128) ? W_out[k*128+c] : 0.f);
    }
}

// ---------------- CSR build ----------------
__global__ void k_zero(int* __restrict__ p, int n) {
    int i = blockIdx.x * 256 + threadIdx.x;
    if (i < n) p[i] = 0;
}

// fused: degree count + pos4 packing
__global__ void k_count(const int* __restrict__ ei, const float* __restrict__ pos,
                        int E, int N, int* __restrict__ cnt, float4* __restrict__ pos4) {
    int i = blockIdx.x * 256 + threadIdx.x;
    if (i < N) pos4[i] = make_float4(pos[3*i], pos[3*i+1], pos[3*i+2], 0.f);
    int T = E + N;
    if (i >= T) return;
    int dst = (i < E) ? ei[E + i] : (i - E);
    atomicAdd(&cnt[dst], 1);
}

__global__ __launch_bounds__(1024) void k_scan1(int* __restrict__ cnt, int* __restrict__ bsum, int N) {
    __shared__ int sc[1024];
    int t = threadIdx.x;
    int i = blockIdx.x * 1024 + t;
    int val = (i < N) ? cnt[i] : 0;
    sc[t] = val;
    __syncthreads();
    for (int off = 1; off < 1024; off <<= 1) {
        int tmp = (t >= off) ? sc[t - off] : 0;
        __syncthreads();
        sc[t] += tmp;
        __syncthreads();
    }
    int incl = sc[t];
    if (i < N) cnt[i] = incl - val;
    if (t == 1023) bsum[blockIdx.x] = incl;
}

__global__ void k_scan2(int* __restrict__ bsum, int* __restrict__ offs, int nb, int N,
                        int* __restrict__ ticket) {
    if (threadIdx.x == 0 && blockIdx.x == 0) {
        int run = 0;
        for (int i = 0; i < nb; ++i) { int tv = bsum[i]; bsum[i] = run; run += tv; }
        offs[N] = run;
        *ticket = 0;                    // re-armed every launch (graph replay safe)
    }
}

__global__ void k_scan3(int* __restrict__ offs, const int* __restrict__ bsum,
                        int* __restrict__ cursor, int N) {
    int i = blockIdx.x * 256 + threadIdx.x;
    if (i < N) {
        int o = offs[i] + bsum[i >> 10];
        offs[i] = o;
        cursor[i] = o;
    }
}

__global__ void k_scatter(const int* __restrict__ ei, int E, int N,
                          int* __restrict__ cursor, int* __restrict__ srcs) {
    int i = blockIdx.x * 256 + threadIdx.x;
    int T = E + N;
    if (i >= T) return;
    int s_, d_;
    if (i < E) { s_ = ei[i]; d_ = ei[E + i]; }
    else       { s_ = i - E; d_ = i - E; }
    int p = atomicAdd(&cursor[d_], 1);
    srcs[p] = s_;
}

// ---------------- node transform via MFMA (interleaved packed outputs) -------------
__global__ __launch_bounds__(512) void k_node2(
    const float* __restrict__ x, const float* __restrict__ b_in,
    const float* __restrict__ bp2, const _Float16* __restrict__ Wnode,
    unsigned int* __restrict__ vpk, unsigned int* __restrict__ pspk,
    unsigned int* __restrict__ pdpk, int N, int nTiles, int nWavesTot)
{
    __shared__ _Float16 WB[3 * 16896];
    __shared__ _Float16 HT[8][16 * 132];
    int tid = threadIdx.x;
    {
        const unsigned int* g = (const unsigned int*)Wnode;
        unsigned int* s = (unsigned int*)WB;
        for (int i = tid; i < 3 * 16896 / 2; i += 512) s[i] = g[i];
    }
    __syncthreads();

    int wid = tid >> 6, lane = tid & 63;
    int l15 = lane & 15, akg = lane >> 4;
    _Float16* ht = HT[wid];

    int gw = blockIdx.x * 8 + wid;
    for (int t = gw; t < nTiles; t += nWavesTot) {
        int row0 = t * 16;
        int rowa = row0 + l15; if (rowa > N - 1) rowa = N - 1;

        f16x8 A[4];
        #pragma unroll
        for (int f = 0; f < 4; ++f)
            A[f] = mkfrag(&x[(size_t)rowa * 128 + f * 32 + akg * 8]);

        #pragma unroll
        for (int ct = 0; ct < 8; ++ct) {
            const _Float16* bb = &WB[(ct * 16 + l15) * 132];
            f32x4 d = {0.f, 0.f, 0.f, 0.f};
            #pragma unroll
            for (int f = 0; f < 4; ++f)
                d = __builtin_amdgcn_mfma_f32_16x16x32_f16(A[f], ldfrag(bb + f * 32 + akg * 8), d, 0, 0, 0);
            float bin = b_in[ct * 16 + l15];
            #pragma unroll
            for (int j = 0; j < 4; ++j)
                ht[(akg * 4 + j) * 132 + ct * 16 + l15] = (_Float16)fmaxf(d[j] + bin, 0.f);
        }

        f16x8 H[4];
        #pragma unroll
        for (int f = 0; f < 4; ++f)
            H[f] = ldfrag(&ht[l15 * 132 + f * 32 + akg * 8]);

        // v = h @ W_lin + bp2 -> vpk (interleaved layout)
        #pragma unroll
        for (int ct = 0; ct < 8; ++ct) {
            const _Float16* bb = &WB[16896 + (ct * 16 + l15) * 132];
            f32x4 d = {0.f, 0.f, 0.f, 0.f};
            #pragma unroll
            for (int f = 0; f < 4; ++f)
                d = __builtin_amdgcn_mfma_f32_16x16x32_f16(H[f], ldfrag(bb + f * 32 + akg * 8), d, 0, 0, 0);
            float bp = bp2[ct * 16 + l15];
            #pragma unroll
            for (int j = 0; j < 4; ++j) {
                float val = d[j] + bp;
                float partner = __shfl_xor(val, 1);
                int row = row0 + akg * 4 + j;
                if (((l15 & 1) == 0) && row < N) {
                    int wold = ct * 8 + (l15 >> 1);
                    vpk[(size_t)row * 64 + (wold & 15) * 4 + (wold >> 4)] = pkrtz(val, partner);
                }
            }
        }

        // ps (ct 0-3) / pd (ct 4-7) -> pspk/pdpk (interleaved layout)
        #pragma unroll
        for (int ct = 0; ct < 8; ++ct) {
            const _Float16* bb = &WB[33792 + (ct * 16 + l15) * 132];
            f32x4 d = {0.f, 0.f, 0.f, 0.f};
            #pragma unroll
            for (int f = 0; f < 4; ++f)
                d = __builtin_amdgcn_mfma_f32_16x16x32_f16(H[f], ldfrag(bb + f * 32 + akg * 8), d, 0, 0, 0);
            #pragma unroll
            for (int j = 0; j < 4; ++j) {
                float val = d[j];
                float partner = __shfl_xor(val, 1);
                int row = row0 + akg * 4 + j;
                if (((l15 & 1) == 0) && row < N) {
                    if (ct < 4) {
                        int wold = ct * 8 + (l15 >> 1);
                        pspk[(size_t)row * 32 + (wold & 15) * 2 + (wold >> 4)] = pkrtz(val, partner);
                    } else {
                        int wold = (ct - 4) * 8 + (l15 >> 1);
                        pdpk[(size_t)row * 32 + (wold & 15) * 2 + (wold >> 4)] = pkrtz(val, partner);
                    }
                }
            }
        }
    }
}

// ---------------- fused edge phase: persistent blocks + dynamic node tickets -------
// 768 blocks = exactly-resident (3 blocks/CU x 256 CU): ONE weight-staging round.
// Dynamic per-wave node assignment via global ticket kills the Poisson-degree
// tail imbalance. Output is assignment-invariant (no races) -> deterministic.
// s_setprio(1) around MFMA clusters (independent unsynced waves: attn-like regime).
__global__ __launch_bounds__(256, 2) void k_edge(
    const unsigned int* __restrict__ vpk, const unsigned int* __restrict__ pspk,
    const unsigned int* __restrict__ pdpk,
    const float4* __restrict__ pos4, const int* __restrict__ srcs,
    const int* __restrict__ offs, const _Float16* __restrict__ Wcat,
    const float* __restrict__ Wp1, const float* __restrict__ bp1,
    const float* __restrict__ bias2, int* __restrict__ ticket,
    float* __restrict__ out, int N)
{
    __shared__ _Float16 WL[320 * 68];
    __shared__ _Float16 PH[4][16 * 68];
    int tid = threadIdx.x;
    {
        const unsigned int* g = (const unsigned int*)Wcat;
        unsigned int* s = (unsigned int*)WL;
        for (int i = tid; i < 320 * 68 / 2; i += 256) s[i] = g[i];
    }
    __syncthreads();

    int wid = tid >> 6, lane = tid & 63;
    int l15 = lane & 15, akg = lane >> 4;
    _Float16* ph  = PH[wid];
    _Float16* ahv = ph;   // alias: ph dead after A0/A1 load

    float wp10 = Wp1[lane], wp11 = Wp1[64 + lane], wp12 = Wp1[128 + lane], bp1l = bp1[lane];
    float bias2_r[4];
    #pragma unroll
    for (int nt = 0; nt < 4; ++nt)
        bias2_r[nt] = bias2[2 * ((nt & 1) * 16 + l15) + (nt >> 1)];

    while (true) {
        int node = 0;
        if (lane == 0) node = atomicAdd(ticket, 1);
        node = __shfl(node, 0);
        if (node >= N) break;

        int beg = offs[node], end = offs[node + 1];
        float4 pi = pos4[node];
        uint2 pd2 = *(const uint2*)&pdpk[(size_t)node * 32 + l15 * 2];   // one 8B gather
        float base4[4];
        #pragma unroll
        for (int nt = 0; nt < 4; ++nt) {
            unsigned int wd = (nt & 1) ? pd2.y : pd2.x;
            base4[nt] = ((nt >> 1) ? h2hi(wd) : h2lo(wd)) + bias2_r[nt];
        }

        float rn[8], rd[8];
        #pragma unroll
        for (int nt = 0; nt < 8; ++nt) { rn[nt] = 0.f; rd[nt] = 0.f; }

        for (int e0 = beg; e0 < end; e0 += 16) {
            int ei_ = e0 + l15;
            int eim = (ei_ < end) ? ei_ : (end - 1);
            int s16 = srcs[eim];
            float4 pj = pos4[s16];
            if (akg == 0) {
                uint2 rr;
                rr.x = pkrtz(pi.x - pj.x, pi.y - pj.y);
                rr.y = pkrtz(pi.z - pj.z, 0.f);
                *(uint2*)&ph[l15 * 68 + 64] = rr;
            }
            #pragma unroll
            for (int ee = 0; ee < 16; ++ee) {
                uint2 rr = *(const uint2*)&ph[ee * 68 + 64];
                float rx = h2lo(rr.x), ry = h2hi(rr.x), rz = h2lo(rr.y);
                float phv = fmaxf(fmaf(rx, wp10, fmaf(ry, wp11, fmaf(rz, wp12, bp1l))), 0.f);
                ph[ee * 68 + lane] = (_Float16)phv;
            }

            f16x8 A0 = ldfrag(&ph[l15 * 68 + akg * 8]);
            f16x8 A1 = ldfrag(&ph[l15 * 68 + 32 + akg * 8]);

            int se[4];
            #pragma unroll
            for (int j = 0; j < 4; ++j) se[j] = __shfl(s16, akg * 4 + j);

            // GEMM1, streamed per nt (pspk: one 8B gather per j)
            {
                unsigned int psw0[4], psw1[4];
                #pragma unroll
                for (int j = 0; j < 4; ++j) {
                    uint2 p2 = *(const uint2*)&pspk[(size_t)se[j] * 32 + l15 * 2];
                    psw0[j] = p2.x; psw1[j] = p2.y;
                }
                __builtin_amdgcn_s_setprio(1);
                #pragma unroll
                for (int nt = 0; nt < 4; ++nt) {
                    const _Float16* br = &WL[(nt * 16 + l15) * 68];
                    f16x8 B0 = ldfrag(br + akg * 8);
                    f16x8 B1 = ldfrag(br + 32 + akg * 8);
                    f32x4 a = {0.f, 0.f, 0.f, 0.f};
                    a = __builtin_amdgcn_mfma_f32_16x16x32_f16(A0, B0, a, 0, 0, 0);
                    a = __builtin_amdgcn_mfma_f32_16x16x32_f16(A1, B1, a, 0, 0, 0);
                    #pragma unroll
                    for (int j = 0; j < 4; ++j) {
                        unsigned int ws = (nt & 1) ? psw1[j] : psw0[j];
                        float psv = (nt >> 1) ? h2hi(ws) : h2lo(ws);
                        float ahf = fmaxf(a[j] + base4[nt] - psv, 0.f);
                        ahv[(akg * 4 + j) * 68 + nt * 16 + l15] = (_Float16)ahf;
                    }
                }
                __builtin_amdgcn_s_setprio(0);
            }

            f16x8 C0 = ldfrag(&ahv[l15 * 68 + akg * 8]);
            f16x8 C1 = ldfrag(&ahv[l15 * 68 + 32 + akg * 8]);

            // GEMM2+3, streamed per (hf,q); vpk: one 8B gather per (j,hf)
            #pragma unroll
            for (int hf = 0; hf < 2; ++hf) {
                unsigned int wvA[4], wvB[4];
                #pragma unroll
                for (int j = 0; j < 4; ++j) {
                    uint2 v2 = *(const uint2*)&vpk[(size_t)se[j] * 64 + l15 * 4 + hf * 2];
                    wvA[j] = v2.x; wvB[j] = v2.y;
                }
                __builtin_amdgcn_s_setprio(1);
                #pragma unroll
                for (int q = 0; q < 4; ++q) {
                    int nt = (q & 1) + hf * 2 + (q >> 1) * 4;
                    const _Float16* br2 = &WL[(64 + nt * 16 + l15) * 68];
                    f16x8 B20 = ldfrag(br2 + akg * 8);
                    f16x8 B21 = ldfrag(br2 + 32 + akg * 8);
                    f32x4 a2 = {0.f, 0.f, 0.f, 0.f};
                    a2 = __builtin_amdgcn_mfma_f32_16x16x32_f16(A0, B20, a2, 0, 0, 0);
                    a2 = __builtin_amdgcn_mfma_f32_16x16x32_f16(A1, B21, a2, 0, 0, 0);
                    const _Float16* br3 = &WL[(192 + nt * 16 + l15) * 68];
                    f16x8 B30 = ldfrag(br3 + akg * 8);
                    f16x8 B31 = ldfrag(br3 + 32 + akg * 8);
                    f32x4 a3 = {0.f, 0.f, 0.f, 0.f};
                    a3 = __builtin_amdgcn_mfma_f32_16x16x32_f16(C0, B30, a3, 0, 0, 0);
                    a3 = __builtin_amdgcn_mfma_f32_16x16x32_f16(C1, B31, a3, 0, 0, 0);
                    #pragma unroll
                    for (int j = 0; j < 4; ++j) {
                        bool vj = (e0 + akg * 4 + j) < end;
                        unsigned int wv = (q & 1) ? wvB[j] : wvA[j];
                        float vv = (q >> 1) ? h2hi(wv) : h2lo(wv);
                        float alpha = vj ? a3[j] : -1e30f;
                        float wexp = __expf(fminf(alpha, 60.f));
                        float u = vv + a2[j];
                        rd[nt] += wexp;
                        rn[nt] = fmaf(wexp, u, rn[nt]);
                    }
                }
                __builtin_amdgcn_s_setprio(0);
            }
        }

        // cross-akg reduce and write
        #pragma unroll
        for (int nt = 0; nt < 8; ++nt) {
            rn[nt] += __shfl_xor(rn[nt], 16);
            rn[nt] += __shfl_xor(rn[nt], 32);
            rd[nt] += __shfl_xor(rd[nt], 16);
            rd[nt] += __shfl_xor(rd[nt], 32);
        }
        if (akg == 0) {
            #pragma unroll
            for (int nt2 = 0; nt2 < 4; ++nt2) {
                float2 o;
                o.x = rn[nt2]     / (rd[nt2]     + 1e-16f);
                o.y = rn[nt2 + 4] / (rd[nt2 + 4] + 1e-16f);
                ((float2*)out)[(size_t)node * 64 + nt2 * 16 + l15] = o;
            }
        }
    }
}

// ---------------- lin_out + residual via MFMA (1 tile per wave) ----------------
__global__ __launch_bounds__(256) void k_out2(
    const float* __restrict__ x, const float* __restrict__ b_out,
    const _Float16* __restrict__ WoutT, float* __restrict__ out,
    int N, int nTiles, int nWavesTot)
{
    __shared__ _Float16 WB[16896];
    int tid = threadIdx.x;
    {
        const unsigned int* g = (const unsigned int*)WoutT;
        unsigned int* s = (unsigned int*)WB;
        for (int i = tid; i < 16896 / 2; i += 256) s[i] = g[i];
    }
    __syncthreads();

    int wid = tid >> 6, lane = tid & 63;
    int l15 = lane & 15, akg = lane >> 4;

    int gw = blockIdx.x * 4 + wid;
    for (int t = gw; t < nTiles; t += nWavesTot) {
        int row0 = t * 16;
        int rowa = row0 + l15; if (rowa > N - 1) rowa = N - 1;

        f16x8 A[4];
        #pragma unroll
        for (int f = 0; f < 4; ++f)
            A[f] = mkfrag(&out[(size_t)rowa * 128 + f * 32 + akg * 8]);

        #pragma unroll
        for (int ct = 0; ct < 8; ++ct) {
            const _Float16* bb = &WB[(ct * 16 + l15) * 132];
            f32x4 d = {0.f, 0.f, 0.f, 0.f};
            #pragma unroll
            for (int f = 0; f < 4; ++f)
                d = __builtin_amdgcn_mfma_f32_16x16x32_f16(A[f], ldfrag(bb + f * 32 + akg * 8), d, 0, 0, 0);
            float bo = b_out[ct * 16 + l15];
            #pragma unroll
            for (int j = 0; j < 4; ++j) {
                int row = row0 + akg * 4 + j;
                if (row < N) {
                    int c = ct * 16 + l15;
                    out[(size_t)row * 128 + c] = fmaxf(d[j] + bo, 0.f) + x[(size_t)row * 128 + c];
                }
            }
        }
    }
}

extern "C" void kernel_launch(void* const* d_in, const int* in_sizes, int n_in,
                              void* d_out, int out_size, void* d_ws, size_t ws_size,
                              hipStream_t stream)
{
    const float* x     = (const float*)d_in[0];
    const float* pos   = (const float*)d_in[1];
    const int*   ei    = (const int*)d_in[2];
    const float* W_in  = (const float*)d_in[3];
    const float* b_in  = (const float*)d_in[4];
    const float* W_out = (const float*)d_in[5];
    const float* b_out = (const float*)d_in[6];
    const float* W_lin = (const float*)d_in[7];
    const float* W_src = (const float*)d_in[8];
    const float* W_dst = (const float*)d_in[9];
    const float* Wp1   = (const float*)d_in[10];
    const float* bp1   = (const float*)d_in[11];
    const float* Wp2   = (const float*)d_in[12];
    const float* bp2   = (const float*)d_in[13];
    const float* Wa1   = (const float*)d_in[14];
    const float* ba1   = (const float*)d_in[15];
    const float* Wa2   = (const float*)d_in[16];
    const float* ba2   = (const float*)d_in[17];
    (void)ba2; // cancels exactly in num/den

    int N = in_sizes[0] / 128;
    int E = in_sizes[2] / 2;
    int T = E + N;
    int nTiles = (N + 15) / 16;
    float* out = (float*)d_out;

    char* w = (char*)d_ws;
    auto alloc = [&](size_t bytes) -> char* {
        char* p = w;
        w += (bytes + 255) & ~(size_t)255;
        return p;
    };
    unsigned int* vpk  = (unsigned int*)alloc((size_t)N * 64 * 4);
    unsigned int* pspk = (unsigned int*)alloc((size_t)N * 32 * 4);
    unsigned int* pdpk = (unsigned int*)alloc((size_t)N * 32 * 4);
    float4* pos4 = (float4*)alloc((size_t)N * 16);
    float* bias2 = (float*)alloc(64 * 4);
    _Float16* Wcat  = (_Float16*)alloc(21760 * 2);
    _Float16* Wnode = (_Float16*)alloc(3 * 16896 * 2);
    _Float16* WoutT = (_Float16*)alloc(16896 * 2);
    int*   offs  = (int*)alloc((size_t)(N + 1) * 4);
    int*   cursor= (int*)alloc((size_t)N * 4);
    int*   bsum  = (int*)alloc(256 * 4);
    int*   ticket= (int*)alloc(256);
    int*   srcs  = (int*)alloc((size_t)T * 4);

    k_pre<<<dim3((89408 + 255) / 256), dim3(256), 0, stream>>>(
        W_src, W_dst, Wa1, ba1, Wp2, bp2, Wa2, W_in, W_lin, W_out,
        bias2, Wcat, Wnode, WoutT);
    k_zero<<<dim3((N + 1 + 255) / 256), dim3(256), 0, stream>>>(offs, N + 1);
    k_count<<<dim3((T + 255) / 256), dim3(256), 0, stream>>>(ei, pos, E, N, offs, pos4);
    int nb = (N + 1023) / 1024;
    k_scan1<<<dim3(nb), dim3(1024), 0, stream>>>(offs, bsum, N);
    k_scan2<<<dim3(1), dim3(64), 0, stream>>>(bsum, offs, nb, N, ticket);
    k_scan3<<<dim3((N + 255) / 256), dim3(256), 0, stream>>>(offs, bsum, cursor, N);
    k_scatter<<<dim3((T + 255) / 256), dim3(256), 0, stream>>>(ei, E, N, cursor, srcs);

    int nodeBlocks = (nTiles + 7) / 8;                 // 1 tile per wave
    k_node2<<<dim3(nodeBlocks), dim3(512), 0, stream>>>(x, b_in, bp2, Wnode,
                                                        vpk, pspk, pdpk, N, nTiles,
                                                        nodeBlocks * 8);
    k_edge<<<dim3(768), dim3(256), 0, stream>>>(vpk, pspk, pdpk, pos4, srcs, offs, Wcat,
                                                Wp1, bp1, bias2, ticket,
                                                out, N);
    int outBlocks = (nTiles + 3) / 4;                  // 1 tile per wave
    k_out2<<<dim3(outBlocks), dim3(256), 0, stream>>>(x, b_out, WoutT, out, N, nTiles,
                                                      outBlocks * 4);
}

// Round 21
// 311.533 us; speedup vs baseline: 2.3677x; 2.3677x over previous
//
#include <hip/hip_runtime.h>

typedef _Float16 h2_t __attribute__((ext_vector_type(2)));
typedef _Float16 f16x4v __attribute__((ext_vector_type(4)));
typedef _Float16 f16x8 __attribute__((ext_vector_type(8)));
typedef float f32x4 __attribute__((ext_vector_type(4)));

struct F8pair { f16x4v lo, hi; };
static __device__ __forceinline__ f16x8 ldfrag(const _Float16* p) {
    F8pair r;
    r.lo = *(const f16x4v*)p;
    r.hi = *(const f16x4v*)(p + 4);
    return __builtin_bit_cast(f16x8, r);
}

static __device__ __forceinline__ unsigned int pkrtz(float a, float b) {
    return __builtin_bit_cast(unsigned int, __builtin_amdgcn_cvt_pkrtz(a, b));
}

static __device__ __forceinline__ float h2lo(unsigned int w) {
    h2_t h = __builtin_bit_cast(h2_t, w);
    return (float)h.x;
}
static __device__ __forceinline__ float h2hi(unsigned int w) {
    h2_t h = __builtin_bit_cast(h2_t, w);
    return (float)h.y;
}

// build f16x8 A-fragment from 8 consecutive fp32 values
static __device__ __forceinline__ f16x8 mkfrag(const float* p) {
    float4 a = ((const float4*)p)[0];
    float4 b = ((const float4*)p)[1];
    uint4 u;
    u.x = pkrtz(a.x, a.y); u.y = pkrtz(a.z, a.w);
    u.z = pkrtz(b.x, b.y); u.w = pkrtz(b.z, b.w);
    return __builtin_bit_cast(f16x8, u);
}

// ---------------- precompute: folded + transposed fp16 weights ----------------
__global__ void k_pre(const float* __restrict__ W_src, const float* __restrict__ W_dst,
                      const float* __restrict__ Wa1, const float* __restrict__ ba1,
                      const float* __restrict__ Wp2, const float* __restrict__ bp2,
                      const float* __restrict__ Wa2, const float* __restrict__ W_in,
                      const float* __restrict__ W_lin, const float* __restrict__ W_out,
                      float* __restrict__ bias2, _Float16* __restrict__ Wcat,
                      _Float16* __restrict__ Wnode, _Float16* __restrict__ WoutT)
{
    int idx = blockIdx.x * 256 + threadIdx.x;
    if (idx < 64) {
        int l = idx;
        float a = ba1[l];
        for (int c = 0; c < 128; ++c) a = fmaf(bp2[c], Wa1[c*64+l], a);
        bias2[l] = a;
    } else if (idx < 64 + 21760) {
        int j = idx - 64;
        int row = j / 68, k = j % 68;
        float val = 0.f;
        if (k < 64) {
            if (row < 64) {
                int Q = 2 * (row & 31) + (row >> 5);
                float a = 0.f;
                for (int c = 0; c < 128; ++c) a = fmaf(Wp2[k*128+c], Wa1[c*64+Q], a);
                val = a;
            } else if (row < 192) {
                int cpos = row - 64;
                int P = 2 * (cpos & 63) + (cpos >> 6);
                val = Wp2[k*128 + P];
            } else {
                int cpos = row - 192;
                int P = 2 * (cpos & 63) + (cpos >> 6);
                int Qk = 2 * (k & 31) + (k >> 5);
                val = Wa2[Qk*128 + P];
            }
        }
        Wcat[j] = (_Float16)val;
    } else if (idx < 21824 + 16896) {          // WinT
        int j = idx - 21824;
        int c = j / 132, k = j % 132;
        Wnode[j] = (_Float16)((k < 128) ? W_in[k*128+c] : 0.f);
    } else if (idx < 38720 + 16896) {          // WlinT
        int j = idx - 38720;
        int c = j / 132, k = j % 132;
        Wnode[16896 + j] = (_Float16)((k < 128) ? W_lin[k*128+c] : 0.f);
    } else if (idx < 55616 + 16896) {          // WpsdT (folded)
        int j = idx - 55616;
        int c = j / 132, k = j % 132;
        float val = 0.f;
        if (k < 128) {
            if (c < 64) {
                for (int q = 0; q < 128; ++q) val = fmaf(W_src[k*128+q], Wa1[q*64+c], val);
            } else {
                for (int q = 0; q < 128; ++q) val = fmaf(W_dst[k*128+q], Wa1[q*64+(c-64)], val);
            }
        }
        Wnode[33792 + j] = (_Float16)val;
    } else if (idx < 72512 + 16896) {          // WoutT
        int j = idx - 72512;
        int c = j / 132, k = j % 132;
        WoutT[j] = (_Float16)((k < 128) ? W_out[k*128+c] : 0.f);
    }
}

// ---------------- CSR build ----------------
__global__ void k_zero(int* __restrict__ p, int n) {
    int i = blockIdx.x * 256 + threadIdx.x;
    if (i < n) p[i] = 0;
}

// fused: degree count + pos4 packing
__global__ void k_count(const int* __restrict__ ei, const float* __restrict__ pos,
                        int E, int N, int* __restrict__ cnt, float4* __restrict__ pos4) {
    int i = blockIdx.x * 256 + threadIdx.x;
    if (i < N) pos4[i] = make_float4(pos[3*i], pos[3*i+1], pos[3*i+2], 0.f);
    int T = E + N;
    if (i >= T) return;
    int dst = (i < E) ? ei[E + i] : (i - E);
    atomicAdd(&cnt[dst], 1);
}

__global__ __launch_bounds__(1024) void k_scan1(int* __restrict__ cnt, int* __restrict__ bsum, int N) {
    __shared__ int sc[1024];
    int t = threadIdx.x;
    int i = blockIdx.x * 1024 + t;
    int val = (i < N) ? cnt[i] : 0;
    sc[t] = val;
    __syncthreads();
    for (int off = 1; off < 1024; off <<= 1) {
        int tmp = (t >= off) ? sc[t - off] : 0;
        __syncthreads();
        sc[t] += tmp;
        __syncthreads();
    }
    int incl = sc[t];
    if (i < N) cnt[i] = incl - val;
    if (t == 1023) bsum[blockIdx.x] = incl;
}

__global__ void k_scan2(int* __restrict__ bsum, int* __restrict__ offs, int nb, int N) {
    if (threadIdx.x == 0 && blockIdx.x == 0) {
        int run = 0;
        for (int i = 0; i < nb; ++i) { int tv = bsum[i]; bsum[i] = run; run += tv; }
        offs[N] = run;
    }
}

__global__ void k_scan3(int* __restrict__ offs, const int* __restrict__ bsum,
                        int* __restrict__ cursor, int N) {
    int i = blockIdx.x * 256 + threadIdx.x;
    if (i < N) {
        int o = offs[i] + bsum[i >> 10];
        offs[i] = o;
        cursor[i] = o;
    }
}

__global__ void k_scatter(const int* __restrict__ ei, int E, int N,
                          int* __restrict__ cursor, int* __restrict__ srcs) {
    int i = blockIdx.x * 256 + threadIdx.x;
    int T = E + N;
    if (i >= T) return;
    int s_, d_;
    if (i < E) { s_ = ei[i]; d_ = ei[E + i]; }
    else       { s_ = i - E; d_ = i - E; }
    int p = atomicAdd(&cursor[d_], 1);
    srcs[p] = s_;
}

// ---------------- node transform via MFMA (interleaved packed outputs) -------------
__global__ __launch_bounds__(512) void k_node2(
    const float* __restrict__ x, const float* __restrict__ b_in,
    const float* __restrict__ bp2, const _Float16* __restrict__ Wnode,
    unsigned int* __restrict__ vpk, unsigned int* __restrict__ pspk,
    unsigned int* __restrict__ pdpk, int N, int nTiles, int nWavesTot)
{
    __shared__ _Float16 WB[3 * 16896];
    __shared__ _Float16 HT[8][16 * 132];
    int tid = threadIdx.x;
    {
        const unsigned int* g = (const unsigned int*)Wnode;
        unsigned int* s = (unsigned int*)WB;
        for (int i = tid; i < 3 * 16896 / 2; i += 512) s[i] = g[i];
    }
    __syncthreads();

    int wid = tid >> 6, lane = tid & 63;
    int l15 = lane & 15, akg = lane >> 4;
    _Float16* ht = HT[wid];

    int gw = blockIdx.x * 8 + wid;
    for (int t = gw; t < nTiles; t += nWavesTot) {
        int row0 = t * 16;
        int rowa = row0 + l15; if (rowa > N - 1) rowa = N - 1;

        f16x8 A[4];
        #pragma unroll
        for (int f = 0; f < 4; ++f)
            A[f] = mkfrag(&x[(size_t)rowa * 128 + f * 32 + akg * 8]);

        #pragma unroll
        for (int ct = 0; ct < 8; ++ct) {
            const _Float16* bb = &WB[(ct * 16 + l15) * 132];
            f32x4 d = {0.f, 0.f, 0.f, 0.f};
            #pragma unroll
            for (int f = 0; f < 4; ++f)
                d = __builtin_amdgcn_mfma_f32_16x16x32_f16(A[f], ldfrag(bb + f * 32 + akg * 8), d, 0, 0, 0);
            float bin = b_in[ct * 16 + l15];
            #pragma unroll
            for (int j = 0; j < 4; ++j)
                ht[(akg * 4 + j) * 132 + ct * 16 + l15] = (_Float16)fmaxf(d[j] + bin, 0.f);
        }

        f16x8 H[4];
        #pragma unroll
        for (int f = 0; f < 4; ++f)
            H[f] = ldfrag(&ht[l15 * 132 + f * 32 + akg * 8]);

        // v = h @ W_lin + bp2 -> vpk (interleaved layout)
        #pragma unroll
        for (int ct = 0; ct < 8; ++ct) {
            const _Float16* bb = &WB[16896 + (ct * 16 + l15) * 132];
            f32x4 d = {0.f, 0.f, 0.f, 0.f};
            #pragma unroll
            for (int f = 0; f < 4; ++f)
                d = __builtin_amdgcn_mfma_f32_16x16x32_f16(H[f], ldfrag(bb + f * 32 + akg * 8), d, 0, 0, 0);
            float bp = bp2[ct * 16 + l15];
            #pragma unroll
            for (int j = 0; j < 4; ++j) {
                float val = d[j] + bp;
                float partner = __shfl_xor(val, 1);
                int row = row0 + akg * 4 + j;
                if (((l15 & 1) == 0) && row < N) {
                    int wold = ct * 8 + (l15 >> 1);
                    vpk[(size_t)row * 64 + (wold & 15) * 4 + (wold >> 4)] = pkrtz(val, partner);
                }
            }
        }

        // ps (ct 0-3) / pd (ct 4-7) -> pspk/pdpk (interleaved layout)
        #pragma unroll
        for (int ct = 0; ct < 8; ++ct) {
            const _Float16* bb = &WB[33792 + (ct * 16 + l15) * 132];
            f32x4 d = {0.f, 0.f, 0.f, 0.f};
            #pragma unroll
            for (int f = 0; f < 4; ++f)
                d = __builtin_amdgcn_mfma_f32_16x16x32_f16(H[f], ldfrag(bb + f * 32 + akg * 8), d, 0, 0, 0);
            #pragma unroll
            for (int j = 0; j < 4; ++j) {
                float val = d[j];
                float partner = __shfl_xor(val, 1);
                int row = row0 + akg * 4 + j;
                if (((l15 & 1) == 0) && row < N) {
                    if (ct < 4) {
                        int wold = ct * 8 + (l15 >> 1);
                        pspk[(size_t)row * 32 + (wold & 15) * 2 + (wold >> 4)] = pkrtz(val, partner);
                    } else {
                        int wold = (ct - 4) * 8 + (l15 >> 1);
                        pdpk[(size_t)row * 32 + (wold & 15) * 2 + (wold >> 4)] = pkrtz(val, partner);
                    }
                }
            }
        }
    }
}

// ---------------- fused edge phase (best-measured config, round 18) ----------------
__global__ __launch_bounds__(512) void k_edge(
    const unsigned int* __restrict__ vpk, const unsigned int* __restrict__ pspk,
    const unsigned int* __restrict__ pdpk,
    const float4* __restrict__ pos4, const int* __restrict__ srcs,
    const int* __restrict__ offs, const _Float16* __restrict__ Wcat,
    const float* __restrict__ Wp1, const float* __restrict__ bp1,
    const float* __restrict__ bias2,
    float* __restrict__ out, int N, int nWavesTot)
{
    __shared__ _Float16 WL[320 * 68];
    __shared__ _Float16 PH[8][16 * 68];
    int tid = threadIdx.x;
    {
        const unsigned int* g = (const unsigned int*)Wcat;
        unsigned int* s = (unsigned int*)WL;
        for (int i = tid; i < 320 * 68 / 2; i += 512) s[i] = g[i];
    }
    __syncthreads();

    int wid = tid >> 6, lane = tid & 63;
    int l15 = lane & 15, akg = lane >> 4;
    _Float16* ph  = PH[wid];
    _Float16* ahv = ph;   // alias: ph dead after A0/A1 load

    float wp10 = Wp1[lane], wp11 = Wp1[64 + lane], wp12 = Wp1[128 + lane], bp1l = bp1[lane];
    float bias2_r[4];
    #pragma unroll
    for (int nt = 0; nt < 4; ++nt)
        bias2_r[nt] = bias2[2 * ((nt & 1) * 16 + l15) + (nt >> 1)];

    int gw = blockIdx.x * 8 + wid;
    for (int node = gw; node < N; node += nWavesTot) {
        int beg = offs[node], end = offs[node + 1];
        float4 pi = pos4[node];
        uint2 pd2 = *(const uint2*)&pdpk[(size_t)node * 32 + l15 * 2];   // one 8B gather
        float base4[4];
        #pragma unroll
        for (int nt = 0; nt < 4; ++nt) {
            unsigned int wd = (nt & 1) ? pd2.y : pd2.x;
            base4[nt] = ((nt >> 1) ? h2hi(wd) : h2lo(wd)) + bias2_r[nt];
        }

        float rn[8], rd[8];
        #pragma unroll
        for (int nt = 0; nt < 8; ++nt) { rn[nt] = 0.f; rd[nt] = 0.f; }

        for (int e0 = beg; e0 < end; e0 += 16) {
            int ei_ = e0 + l15;
            int eim = (ei_ < end) ? ei_ : (end - 1);
            int s16 = srcs[eim];
            float4 pj = pos4[s16];
            if (akg == 0) {
                uint2 rr;
                rr.x = pkrtz(pi.x - pj.x, pi.y - pj.y);
                rr.y = pkrtz(pi.z - pj.z, 0.f);
                *(uint2*)&ph[l15 * 68 + 64] = rr;
            }
            #pragma unroll
            for (int ee = 0; ee < 16; ++ee) {
                uint2 rr = *(const uint2*)&ph[ee * 68 + 64];
                float rx = h2lo(rr.x), ry = h2hi(rr.x), rz = h2lo(rr.y);
                float phv = fmaxf(fmaf(rx, wp10, fmaf(ry, wp11, fmaf(rz, wp12, bp1l))), 0.f);
                ph[ee * 68 + lane] = (_Float16)phv;
            }

            f16x8 A0 = ldfrag(&ph[l15 * 68 + akg * 8]);
            f16x8 A1 = ldfrag(&ph[l15 * 68 + 32 + akg * 8]);

            int se[4];
            #pragma unroll
            for (int j = 0; j < 4; ++j) se[j] = __shfl(s16, akg * 4 + j);

            // GEMM1, streamed per nt (pspk: one 8B gather per j)
            {
                unsigned int psw0[4], psw1[4];
                #pragma unroll
                for (int j = 0; j < 4; ++j) {
                    uint2 p2 = *(const uint2*)&pspk[(size_t)se[j] * 32 + l15 * 2];
                    psw0[j] = p2.x; psw1[j] = p2.y;
                }
                #pragma unroll
                for (int nt = 0; nt < 4; ++nt) {
                    const _Float16* br = &WL[(nt * 16 + l15) * 68];
                    f16x8 B0 = ldfrag(br + akg * 8);
                    f16x8 B1 = ldfrag(br + 32 + akg * 8);
                    f32x4 a = {0.f, 0.f, 0.f, 0.f};
                    a = __builtin_amdgcn_mfma_f32_16x16x32_f16(A0, B0, a, 0, 0, 0);
                    a = __builtin_amdgcn_mfma_f32_16x16x32_f16(A1, B1, a, 0, 0, 0);
                    #pragma unroll
                    for (int j = 0; j < 4; ++j) {
                        unsigned int ws = (nt & 1) ? psw1[j] : psw0[j];
                        float psv = (nt >> 1) ? h2hi(ws) : h2lo(ws);
                        float ahf = fmaxf(a[j] + base4[nt] - psv, 0.f);
                        ahv[(akg * 4 + j) * 68 + nt * 16 + l15] = (_Float16)ahf;
                    }
                }
            }

            f16x8 C0 = ldfrag(&ahv[l15 * 68 + akg * 8]);
            f16x8 C1 = ldfrag(&ahv[l15 * 68 + 32 + akg * 8]);

            // GEMM2+3, streamed per (hf,q); vpk: one 8B gather per (j,hf)
            #pragma unroll
            for (int hf = 0; hf < 2; ++hf) {
                unsigned int wvA[4], wvB[4];
                #pragma unroll
                for (int j = 0; j < 4; ++j) {
                    uint2 v2 = *(const uint2*)&vpk[(size_t)se[j] * 64 + l15 * 4 + hf * 2];
                    wvA[j] = v2.x; wvB[j] = v2.y;
                }
                #pragma unroll
                for (int q = 0; q < 4; ++q) {
                    int nt = (q & 1) + hf * 2 + (q >> 1) * 4;
                    const _Float16* br2 = &WL[(64 + nt * 16 + l15) * 68];
                    f16x8 B20 = ldfrag(br2 + akg * 8);
                    f16x8 B21 = ldfrag(br2 + 32 + akg * 8);
                    f32x4 a2 = {0.f, 0.f, 0.f, 0.f};
                    a2 = __builtin_amdgcn_mfma_f32_16x16x32_f16(A0, B20, a2, 0, 0, 0);
                    a2 = __builtin_amdgcn_mfma_f32_16x16x32_f16(A1, B21, a2, 0, 0, 0);
                    const _Float16* br3 = &WL[(192 + nt * 16 + l15) * 68];
                    f16x8 B30 = ldfrag(br3 + akg * 8);
                    f16x8 B31 = ldfrag(br3 + 32 + akg * 8);
                    f32x4 a3 = {0.f, 0.f, 0.f, 0.f};
                    a3 = __builtin_amdgcn_mfma_f32_16x16x32_f16(C0, B30, a3, 0, 0, 0);
                    a3 = __builtin_amdgcn_mfma_f32_16x16x32_f16(C1, B31, a3, 0, 0, 0);
                    #pragma unroll
                    for (int j = 0; j < 4; ++j) {
                        bool vj = (e0 + akg * 4 + j) < end;
                        unsigned int wv = (q & 1) ? wvB[j] : wvA[j];
                        float vv = (q >> 1) ? h2hi(wv) : h2lo(wv);
                        float alpha = vj ? a3[j] : -1e30f;
                        float wexp = __expf(fminf(alpha, 60.f));
                        float u = vv + a2[j];
                        rd[nt] += wexp;
                        rn[nt] = fmaf(wexp, u, rn[nt]);
                    }
                }
            }
        }

        // cross-akg reduce and write
        #pragma unroll
        for (int nt = 0; nt < 8; ++nt) {
            rn[nt] += __shfl_xor(rn[nt], 16);
            rn[nt] += __shfl_xor(rn[nt], 32);
            rd[nt] += __shfl_xor(rd[nt], 16);
            rd[nt] += __shfl_xor(rd[nt], 32);
        }
        if (akg == 0) {
            #pragma unroll
            for (int nt2 = 0; nt2 < 4; ++nt2) {
                float2 o;
                o.x = rn[nt2]     / (rd[nt2]     + 1e-16f);
                o.y = rn[nt2 + 4] / (rd[nt2 + 4] + 1e-16f);
                ((float2*)out)[(size_t)node * 64 + nt2 * 16 + l15] = o;
            }
        }
    }
}

// ---------------- lin_out + residual via MFMA (1 tile per wave) ----------------
__global__ __launch_bounds__(256) void k_out2(
    const float* __restrict__ x, const float* __restrict__ b_out,
    const _Float16* __restrict__ WoutT, float* __restrict__ out,
    int N, int nTiles, int nWavesTot)
{
    __shared__ _Float16 WB[16896];
    int tid = threadIdx.x;
    {
        const unsigned int* g = (const unsigned int*)WoutT;
        unsigned int* s = (unsigned int*)WB;
        for (int i = tid; i < 16896 / 2; i += 256) s[i] = g[i];
    }
    __syncthreads();

    int wid = tid >> 6, lane = tid & 63;
    int l15 = lane & 15, akg = lane >> 4;

    int gw = blockIdx.x * 4 + wid;
    for (int t = gw; t < nTiles; t += nWavesTot) {
        int row0 = t * 16;
        int rowa = row0 + l15; if (rowa > N - 1) rowa = N - 1;

        f16x8 A[4];
        #pragma unroll
        for (int f = 0; f < 4; ++f)
            A[f] = mkfrag(&out[(size_t)rowa * 128 + f * 32 + akg * 8]);

        #pragma unroll
        for (int ct = 0; ct < 8; ++ct) {
            const _Float16* bb = &WB[(ct * 16 + l15) * 132];
            f32x4 d = {0.f, 0.f, 0.f, 0.f};
            #pragma unroll
            for (int f = 0; f < 4; ++f)
                d = __builtin_amdgcn_mfma_f32_16x16x32_f16(A[f], ldfrag(bb + f * 32 + akg * 8), d, 0, 0, 0);
            float bo = b_out[ct * 16 + l15];
            #pragma unroll
            for (int j = 0; j < 4; ++j) {
                int row = row0 + akg * 4 + j;
                if (row < N) {
                    int c = ct * 16 + l15;
                    out[(size_t)row * 128 + c] = fmaxf(d[j] + bo, 0.f) + x[(size_t)row * 128 + c];
                }
            }
        }
    }
}

extern "C" void kernel_launch(void* const* d_in, const int* in_sizes, int n_in,
                              void* d_out, int out_size, void* d_ws, size_t ws_size,
                              hipStream_t stream)
{
    const float* x     = (const float*)d_in[0];
    const float* pos   = (const float*)d_in[1];
    const int*   ei    = (const int*)d_in[2];
    const float* W_in  = (const float*)d_in[3];
    const float* b_in  = (const float*)d_in[4];
    const float* W_out = (const float*)d_in[5];
    const float* b_out = (const float*)d_in[6];
    const float* W_lin = (const float*)d_in[7];
    const float* W_src = (const float*)d_in[8];
    const float* W_dst = (const float*)d_in[9];
    const float* Wp1   = (const float*)d_in[10];
    const float* bp1   = (const float*)d_in[11];
    const float* Wp2   = (const float*)d_in[12];
    const float* bp2   = (const float*)d_in[13];
    const float* Wa1   = (const float*)d_in[14];
    const float* ba1   = (const float*)d_in[15];
    const float* Wa2   = (const float*)d_in[16];
    const float* ba2   = (const float*)d_in[17];
    (void)ba2; // cancels exactly in num/den

    int N = in_sizes[0] / 128;
    int E = in_sizes[2] / 2;
    int T = E + N;
    int nTiles = (N + 15) / 16;
    float* out = (float*)d_out;

    char* w = (char*)d_ws;
    auto alloc = [&](size_t bytes) -> char* {
        char* p = w;
        w += (bytes + 255) & ~(size_t)255;
        return p;
    };
    unsigned int* vpk  = (unsigned int*)alloc((size_t)N * 64 * 4);
    unsigned int* pspk = (unsigned int*)alloc((size_t)N * 32 * 4);
    unsigned int* pdpk = (unsigned int*)alloc((size_t)N * 32 * 4);
    float4* pos4 = (float4*)alloc((size_t)N * 16);
    float* bias2 = (float*)alloc(64 * 4);
    _Float16* Wcat  = (_Float16*)alloc(21760 * 2);
    _Float16* Wnode = (_Float16*)alloc(3 * 16896 * 2);
    _Float16* WoutT = (_Float16*)alloc(16896 * 2);
    int*   offs  = (int*)alloc((size_t)(N + 1) * 4);
    int*   cursor= (int*)alloc((size_t)N * 4);
    int*   bsum  = (int*)alloc(256 * 4);
    int*   srcs  = (int*)alloc((size_t)T * 4);

    k_pre<<<dim3((89408 + 255) / 256), dim3(256), 0, stream>>>(
        W_src, W_dst, Wa1, ba1, Wp2, bp2, Wa2, W_in, W_lin, W_out,
        bias2, Wcat, Wnode, WoutT);
    k_zero<<<dim3((N + 1 + 255) / 256), dim3(256), 0, stream>>>(offs, N + 1);
    k_count<<<dim3((T + 255) / 256), dim3(256), 0, stream>>>(ei, pos, E, N, offs, pos4);
    int nb = (N + 1023) / 1024;
    k_scan1<<<dim3(nb), dim3(1024), 0, stream>>>(offs, bsum, N);
    k_scan2<<<dim3(1), dim3(64), 0, stream>>>(bsum, offs, nb, N);
    k_scan3<<<dim3((N + 255) / 256), dim3(256), 0, stream>>>(offs, bsum, cursor, N);
    k_scatter<<<dim3((T + 255) / 256), dim3(256), 0, stream>>>(ei, E, N, cursor, srcs);

    int nodeBlocks = (nTiles + 7) / 8;                 // 1 tile per wave
    k_node2<<<dim3(nodeBlocks), dim3(512), 0, stream>>>(x, b_in, bp2, Wnode,
                                                        vpk, pspk, pdpk, N, nTiles,
                                                        nodeBlocks * 8);
    int nWavesTot = 8192;
    k_edge<<<dim3(1024), dim3(512), 0, stream>>>(vpk, pspk, pdpk, pos4, srcs, offs, Wcat,
                                                 Wp1, bp1, bias2,
                                                 out, N, nWavesTot);
    int outBlocks = (nTiles + 3) / 4;                  // 1 tile per wave
    k_out2<<<dim3(outBlocks), dim3(256), 0, stream>>>(x, b_out, WoutT, out, N, nTiles,
                                                      outBlocks * 4);
}